// Round 10
// baseline (364.583 us; speedup 1.0000x reference)
//
#include <hip/hip_runtime.h>
#include <math.h>

#define D_STATE 16
#define D_INNER 2048
#define SEQ     2048
#define BSZ     2
#define NTOK    (BSZ*SEQ)   // 4096
#define CH      32           // scan chunk length
#define NCHK    (SEQ/CH)     // 64 chunks per sequence
#define PHN     ((size_t)BSZ * NCHK * 2048 * 16)   // floats per P/Hl plane

typedef __bf16 bf16x8 __attribute__((ext_vector_type(8)));
typedef float  floatx4 __attribute__((ext_vector_type(4)));

__device__ __forceinline__ unsigned short f2bf(float f) {  // RNE fp32->bf16
  unsigned int u = __float_as_uint(f);
  u += 0x7fff + ((u >> 16) & 1);
  return (unsigned short)(u >> 16);
}
__device__ __forceinline__ float bf2f(unsigned short u) {
  return __uint_as_float((unsigned int)u << 16);
}

__device__ __forceinline__ void gload16(const unsigned short* g, unsigned short* l) {
  __builtin_amdgcn_global_load_lds(
      (const __attribute__((address_space(1))) unsigned int*)g,
      (__attribute__((address_space(3))) unsigned int*)l, 16, 0, 0);
}

// ---------------------------------------------------------------------------
// Mega-cast: x + 4 weight matrices fp32->bf16 in one dispatch.
// ---------------------------------------------------------------------------
#define N_X   (NTOK*1024)      // 4194304
#define N_WI  (4096*1024)      // 4194304
#define N_WX  (96*2048)        // 196608
#define N_WD  (2048*64)        // 131072
#define N_WO  (1024*2048)      // 2097152
#define N_ALL (N_X+N_WI+N_WX+N_WD+N_WO)   // 10813440

__global__ __launch_bounds__(256) void cast5_k(
    const float* __restrict__ sx, unsigned short* __restrict__ dx,
    const float* __restrict__ swi, unsigned short* __restrict__ dwi,
    const float* __restrict__ swx, unsigned short* __restrict__ dwx,
    const float* __restrict__ swd, unsigned short* __restrict__ dwd,
    const float* __restrict__ swo, unsigned short* __restrict__ dwo)
{
  int i = (blockIdx.x * 256 + threadIdx.x) * 4;
  const float* s; unsigned short* d;
  if      (i < N_X)                  { s = sx  + i;                      d = dx  + i; }
  else if (i < N_X+N_WI)             { s = swi + (i - N_X);              d = dwi + (i - N_X); }
  else if (i < N_X+N_WI+N_WX)        { s = swx + (i - N_X-N_WI);         d = dwx + (i - N_X-N_WI); }
  else if (i < N_X+N_WI+N_WX+N_WD)   { s = swd + (i - N_X-N_WI-N_WX);    d = dwd + (i - N_X-N_WI-N_WX); }
  else if (i < N_ALL)                { s = swo + (i - N_X-N_WI-N_WX-N_WD); d = dwo + (i - N_X-N_WI-N_WX-N_WD); }
  else return;
  float4 v = *(const float4*)s;
  ushort4 o;
  o.x = f2bf(v.x); o.y = f2bf(v.y); o.z = f2bf(v.z); o.w = f2bf(v.w);
  *(ushort4*)d = o;
}

// Fused: sum 8 bf16 K-slice partials of x_proj -> xdbl fp32 + dt_r bf16 (stride 64).
__global__ __launch_bounds__(256) void redcast_k(
    const unsigned short* __restrict__ p, float* __restrict__ dst,
    unsigned short* __restrict__ dtr)
{
  int i = (blockIdx.x * 256 + threadIdx.x) * 4;   // over 4096*96
  float4 s = {0.f, 0.f, 0.f, 0.f};
#pragma unroll
  for (int z = 0; z < 8; ++z) {
    ushort4 v = *(const ushort4*)(p + (size_t)z * (4096 * 96) + i);
    s.x += bf2f(v.x); s.y += bf2f(v.y); s.z += bf2f(v.z); s.w += bf2f(v.w);
  }
  *(float4*)(dst + i) = s;
  int m = i / 96, col = i - m * 96;
  if (col < 64) {
    ushort4 o;
    o.x = f2bf(s.x); o.y = f2bf(s.y); o.z = f2bf(s.z); o.w = f2bf(s.w);
    *(ushort4*)(dtr + (size_t)m * 64 + col) = o;
  }
}

// ---------------------------------------------------------------------------
// bf16 MFMA GEMM, BK=64 via two 32-col LDS planes (one barrier pair per 64 K).
// 128x128 tile, 256 thr, 4x4 16x16x32 frags/wave, 2-way-conflict LDS swizzle.
// Split-K via blockIdx.z (slice ksl, out += z*slicesz). ksl % 64 == 0.
// MODE 0: fp32 out (split ok)   MODE 1: bf16 softplus(acc+aux[n])
// MODE 3: bf16 out              MODE 4: bf16 out (split partials)
// ---------------------------------------------------------------------------
template<int MODE>
__global__ __launch_bounds__(256) void mgemm(
    const unsigned short* __restrict__ A, int lda,
    const unsigned short* __restrict__ W, int ldw,
    void* __restrict__ Cv_, int ldc,
    int N, int ksl, const float* __restrict__ aux, size_t slicesz)
{
  __shared__ unsigned short As[2][128 * 32];
  __shared__ unsigned short Ws[2][128 * 32];
  const int tid  = threadIdx.x;
  const int wave = tid >> 6, lane = tid & 63;
  const int m0 = blockIdx.y * 128, n0 = blockIdx.x * 128;
  const int k0 = blockIdx.z * ksl;
  const int srow = lane >> 2;
  const int scol = ((((lane & 3) + 4) - ((lane >> 3) & 3)) & 3) * 8;
  const int fr = lane & 15, fq = lane >> 4;
  const int sw = (fr >> 1) & 3;
  const int wm = (wave >> 1) * 64, wn = (wave & 1) * 64;

  const int ar0 = (wave * 2 + 0) * 16 + srow;
  const int ar1 = (wave * 2 + 1) * 16 + srow;
  int wr0 = n0 + ar0; if (wr0 > N - 1) wr0 = N - 1;
  int wr1 = n0 + ar1; if (wr1 > N - 1) wr1 = N - 1;
  const unsigned short* gA0 = A + (size_t)(m0 + ar0) * lda + scol;
  const unsigned short* gA1 = A + (size_t)(m0 + ar1) * lda + scol;
  const unsigned short* gW0 = W + (size_t)wr0 * ldw + scol;
  const unsigned short* gW1 = W + (size_t)wr1 * ldw + scol;
  const int lofs0 = (wave * 2 + 0) * 512;
  const int lofs1 = (wave * 2 + 1) * 512;

  floatx4 zero = {0.f, 0.f, 0.f, 0.f};
  floatx4 acc[4][4];
#pragma unroll
  for (int i = 0; i < 4; ++i)
#pragma unroll
    for (int j = 0; j < 4; ++j) acc[i][j] = zero;

  for (int kt = k0; kt < k0 + ksl; kt += 64) {
    __syncthreads();
    gload16(gA0 + kt,      As[0] + lofs0);
    gload16(gA1 + kt,      As[0] + lofs1);
    gload16(gW0 + kt,      Ws[0] + lofs0);
    gload16(gW1 + kt,      Ws[0] + lofs1);
    gload16(gA0 + kt + 32, As[1] + lofs0);
    gload16(gA1 + kt + 32, As[1] + lofs1);
    gload16(gW0 + kt + 32, Ws[1] + lofs0);
    gload16(gW1 + kt + 32, Ws[1] + lofs1);
    __syncthreads();
#pragma unroll
    for (int kb = 0; kb < 2; ++kb) {
      bf16x8 af[4], bfr[4];
      const int cuA = ((fq + sw) & 3) * 8;
#pragma unroll
      for (int i = 0; i < 4; ++i) {
        af[i]  = *(const bf16x8*)(As[kb] + (wm + i * 16 + fr) * 32 + cuA);
        bfr[i] = *(const bf16x8*)(Ws[kb] + (wn + i * 16 + fr) * 32 + cuA);
      }
#pragma unroll
      for (int i = 0; i < 4; ++i)
#pragma unroll
        for (int j = 0; j < 4; ++j)
          acc[i][j] = __builtin_amdgcn_mfma_f32_16x16x32_bf16(af[i], bfr[j], acc[i][j], 0, 0, 0);
    }
  }

  // C/D layout: col = lane&15, row = (lane>>4)*4 + reg
#pragma unroll
  for (int i = 0; i < 4; ++i) {
#pragma unroll
    for (int j = 0; j < 4; ++j) {
      int n = n0 + wn + j * 16 + fr;
      if (n < N) {
#pragma unroll
        for (int r = 0; r < 4; ++r) {
          int m = m0 + wm + i * 16 + fq * 4 + r;
          float v = acc[i][j][r];
          if (MODE == 1) {
            v += aux[n]; v = (v > 20.f) ? v : log1pf(__expf(v));
            ((unsigned short*)Cv_)[(size_t)m * ldc + n] = f2bf(v);
          } else if (MODE == 3) {
            ((unsigned short*)Cv_)[(size_t)m * ldc + n] = f2bf(v);
          } else if (MODE == 4) {
            unsigned short* C = (unsigned short*)Cv_ + (size_t)blockIdx.z * slicesz;
            C[(size_t)m * ldc + n] = f2bf(v);
          } else {
            float* C = (float*)Cv_ + (size_t)blockIdx.z * slicesz;
            C[(size_t)m * ldc + n] = v;
          }
        }
      }
    }
  }
}

// ---------------------------------------------------------------------------
// Depthwise causal conv(4) + bias + SiLU. bf16 in/out, 4 channels per thread.
// ---------------------------------------------------------------------------
__global__ __launch_bounds__(256) void conv_silu_k(
    const unsigned short* __restrict__ xzb, const float* __restrict__ w,
    const float* __restrict__ b, unsigned short* __restrict__ xcb)
{
  int gid = blockIdx.x * 256 + threadIdx.x;    // over NTOK*2048/4
  int e4 = (gid * 4) & 2047;
  int bl = gid >> 9;                            // b*SEQ + l
  int l  = bl & (SEQ - 1);
  float4 acc = *(const float4*)(b + e4);
  float4 w0 = *(const float4*)(w + (e4 + 0) * 4);
  float4 w1 = *(const float4*)(w + (e4 + 1) * 4);
  float4 w2 = *(const float4*)(w + (e4 + 2) * 4);
  float4 w3 = *(const float4*)(w + (e4 + 3) * 4);
  const float* w0p = (const float*)&w0;
  const float* w1p = (const float*)&w1;
  const float* w2p = (const float*)&w2;
  const float* w3p = (const float*)&w3;
#pragma unroll
  for (int k = 0; k < 4; ++k) {
    int ll = l - 3 + k;
    if (ll >= 0) {
      ushort4 xv = *(const ushort4*)(xzb + (size_t)(bl - 3 + k) * 4096 + e4);
      acc.x = fmaf(bf2f(xv.x), w0p[k], acc.x);
      acc.y = fmaf(bf2f(xv.y), w1p[k], acc.y);
      acc.z = fmaf(bf2f(xv.z), w2p[k], acc.z);
      acc.w = fmaf(bf2f(xv.w), w3p[k], acc.w);
    }
  }
  ushort4 o;
  o.x = f2bf(acc.x / (1.f + __expf(-acc.x)));
  o.y = f2bf(acc.y / (1.f + __expf(-acc.y)));
  o.z = f2bf(acc.z / (1.f + __expf(-acc.z)));
  o.w = f2bf(acc.w / (1.f + __expf(-acc.w)));
  *(ushort4*)(xcb + (size_t)gid * 4) = o;
}

// ---------------------------------------------------------------------------
// Chunked selective scan, all 16 states per thread. dt/u bf16, B/C fp32.
// thread t = (b*NCHK + c)*2048 + d.  P at PH[t*16+s], Hl/hin at +PHN.
// ---------------------------------------------------------------------------
__global__ __launch_bounds__(256) void scan_p1(
    const float* __restrict__ A_log,
    const float* __restrict__ x_dbl, const unsigned short* __restrict__ xcb,
    const unsigned short* __restrict__ dtb, float* __restrict__ PH)
{
  const int t = blockIdx.x * 256 + threadIdx.x;
  const int d = t & 2047;
  const int c = (t >> 11) & (NCHK - 1);
  const int b = t >> 17;
  const size_t tok0 = (size_t)b * SEQ + c * CH;
  const float* xd = x_dbl + tok0 * 96;

  float Ac[16];
  {
    float4 a0 = *(const float4*)(A_log + d * 16);
    float4 a1 = *(const float4*)(A_log + d * 16 + 4);
    float4 a2 = *(const float4*)(A_log + d * 16 + 8);
    float4 a3 = *(const float4*)(A_log + d * 16 + 12);
    Ac[0]=-__expf(a0.x); Ac[1]=-__expf(a0.y); Ac[2]=-__expf(a0.z); Ac[3]=-__expf(a0.w);
    Ac[4]=-__expf(a1.x); Ac[5]=-__expf(a1.y); Ac[6]=-__expf(a1.z); Ac[7]=-__expf(a1.w);
    Ac[8]=-__expf(a2.x); Ac[9]=-__expf(a2.y); Ac[10]=-__expf(a2.z); Ac[11]=-__expf(a2.w);
    Ac[12]=-__expf(a3.x); Ac[13]=-__expf(a3.y); Ac[14]=-__expf(a3.z); Ac[15]=-__expf(a3.w);
  }

  float p[16], h[16];
#pragma unroll
  for (int s = 0; s < 16; ++s) { p[s] = 1.f; h[s] = 0.f; }

  for (int l = 0; l < CH; ++l) {
    float dtv = bf2f(dtb[(tok0 + l) * 2048 + d]);
    float uv  = bf2f(xcb[(tok0 + l) * 2048 + d]);
    float du  = dtv * uv;
    float Bv[16];
#pragma unroll
    for (int j = 0; j < 4; ++j) {
      float4 bb = *(const float4*)(xd + l * 96 + 64 + j * 4);
      Bv[j*4+0]=bb.x; Bv[j*4+1]=bb.y; Bv[j*4+2]=bb.z; Bv[j*4+3]=bb.w;
    }
#pragma unroll
    for (int s = 0; s < 16; ++s) {
      float dA = __expf(dtv * Ac[s]);
      p[s] *= dA;
      h[s] = fmaf(dA, h[s], du * Bv[s]);
    }
  }

  float* pp = PH + (size_t)t * 16;
#pragma unroll
  for (int j = 0; j < 4; ++j) {
    *(float4*)(pp + j * 4)       = make_float4(p[j*4], p[j*4+1], p[j*4+2], p[j*4+3]);
    *(float4*)(pp + PHN + j * 4) = make_float4(h[j*4], h[j*4+1], h[j*4+2], h[j*4+3]);
  }
}

// Sequential fix-up over chunks: overwrite Hl[c] with chunk-entry state hin[c].
// Chunk c+1's (P, Hl) prefetched before the dependent FMA on chunk c.
__global__ __launch_bounds__(256) void scan_fix(float* __restrict__ PH)
{
  int tid = blockIdx.x * 256 + threadIdx.x;  // (b*2048+d)*16+s
  int s = tid & 15;
  int d = (tid >> 4) & 2047;
  int b = tid >> 15;
  const size_t cstep = (size_t)2048 * 16;
  size_t idx0 = (((size_t)b * NCHK * 2048) + d) * 16 + s;
  float h = 0.f;
  float p  = PH[idx0];
  float hl = PH[idx0 + PHN];
  for (int c = 0; c < NCHK; ++c) {
    size_t idx = idx0 + (size_t)c * cstep;
    float pn = 0.f, hn = 0.f;
    if (c + 1 < NCHK) {
      pn = PH[idx + cstep];
      hn = PH[idx + cstep + PHN];
    }
    PH[idx + PHN] = h;               // hin for chunk c
    h = fmaf(p, h, hl);
    p = pn; hl = hn;
  }
}

__global__ __launch_bounds__(256) void scan_p2(
    const float* __restrict__ A_log, const float* __restrict__ Dvec,
    const float* __restrict__ x_dbl, const unsigned short* __restrict__ xcb,
    const unsigned short* __restrict__ xzb, const float* __restrict__ PH,
    const unsigned short* __restrict__ dtb, unsigned short* __restrict__ ybf)
{
  const int t = blockIdx.x * 256 + threadIdx.x;
  const int d = t & 2047;
  const int c = (t >> 11) & (NCHK - 1);
  const int b = t >> 17;
  const size_t tok0 = (size_t)b * SEQ + c * CH;
  const float* xd = x_dbl + tok0 * 96;
  const float Dd = Dvec[d];

  float Ac[16];
  {
    float4 a0 = *(const float4*)(A_log + d * 16);
    float4 a1 = *(const float4*)(A_log + d * 16 + 4);
    float4 a2 = *(const float4*)(A_log + d * 16 + 8);
    float4 a3 = *(const float4*)(A_log + d * 16 + 12);
    Ac[0]=-__expf(a0.x); Ac[1]=-__expf(a0.y); Ac[2]=-__expf(a0.z); Ac[3]=-__expf(a0.w);
    Ac[4]=-__expf(a1.x); Ac[5]=-__expf(a1.y); Ac[6]=-__expf(a1.z); Ac[7]=-__expf(a1.w);
    Ac[8]=-__expf(a2.x); Ac[9]=-__expf(a2.y); Ac[10]=-__expf(a2.z); Ac[11]=-__expf(a2.w);
    Ac[12]=-__expf(a3.x); Ac[13]=-__expf(a3.y); Ac[14]=-__expf(a3.z); Ac[15]=-__expf(a3.w);
  }

  const float* pp = PH + (size_t)t * 16;
  float h[16];
#pragma unroll
  for (int j = 0; j < 4; ++j) {
    float4 hh = *(const float4*)(pp + PHN + j * 4);
    h[j*4+0]=hh.x; h[j*4+1]=hh.y; h[j*4+2]=hh.z; h[j*4+3]=hh.w;
  }

  for (int l = 0; l < CH; ++l) {
    float dtv = bf2f(dtb[(tok0 + l) * 2048 + d]);
    float uv  = bf2f(xcb[(tok0 + l) * 2048 + d]);
    float zv  = bf2f(xzb[(tok0 + l) * 4096 + 2048 + d]);
    float du  = dtv * uv;
    float Bv[16], Cv[16];
#pragma unroll
    for (int j = 0; j < 4; ++j) {
      float4 bb = *(const float4*)(xd + l * 96 + 64 + j * 4);
      float4 cc = *(const float4*)(xd + l * 96 + 80 + j * 4);
      Bv[j*4+0]=bb.x; Bv[j*4+1]=bb.y; Bv[j*4+2]=bb.z; Bv[j*4+3]=bb.w;
      Cv[j*4+0]=cc.x; Cv[j*4+1]=cc.y; Cv[j*4+2]=cc.z; Cv[j*4+3]=cc.w;
    }
    float y = 0.f;
#pragma unroll
    for (int s = 0; s < 16; ++s) {
      float dA = __expf(dtv * Ac[s]);
      h[s] = fmaf(dA, h[s], du * Bv[s]);
      y = fmaf(h[s], Cv[s], y);
    }
    y = fmaf(Dd, uv, y);
    y *= zv / (1.f + __expf(-zv));
    ybf[(tok0 + l) * 2048 + d] = f2bf(y);
  }
}

// ---------------------------------------------------------------------------
// Fused: v = bf(p0) + bf(p1) + x  (out_proj bf16 partials + residual), then LN.
// ---------------------------------------------------------------------------
__global__ __launch_bounds__(256) void ln2_k(
    const unsigned short* __restrict__ p0, const unsigned short* __restrict__ p1,
    const float* __restrict__ x, const float* __restrict__ g,
    const float* __restrict__ bb, float* __restrict__ out)
{
  int row = blockIdx.x;
  size_t off = (size_t)row * 1024;
  ushort4 a = ((const ushort4*)(p0 + off))[threadIdx.x];
  ushort4 b = ((const ushort4*)(p1 + off))[threadIdx.x];
  float4 c = ((const float4*)(x  + off))[threadIdx.x];
  float4 v;
  v.x = bf2f(a.x) + bf2f(b.x) + c.x;
  v.y = bf2f(a.y) + bf2f(b.y) + c.y;
  v.z = bf2f(a.z) + bf2f(b.z) + c.z;
  v.w = bf2f(a.w) + bf2f(b.w) + c.w;
  float s  = v.x + v.y + v.z + v.w;
  float sq = v.x * v.x + v.y * v.y + v.z * v.z + v.w * v.w;
#pragma unroll
  for (int o = 32; o >= 1; o >>= 1) {
    s  += __shfl_xor(s,  o, 64);
    sq += __shfl_xor(sq, o, 64);
  }
  __shared__ float red[8];
  int wid = threadIdx.x >> 6;
  if ((threadIdx.x & 63) == 0) { red[wid] = s; red[4 + wid] = sq; }
  __syncthreads();
  s  = red[0] + red[1] + red[2] + red[3];
  sq = red[4] + red[5] + red[6] + red[7];
  float mu  = s * (1.f / 1024.f);
  float var = sq * (1.f / 1024.f) - mu * mu;
  float r   = rsqrtf(var + 1e-5f);
  int col = threadIdx.x * 4;
  float4 gv = *(const float4*)(g + col);
  float4 bv = *(const float4*)(bb + col);
  float4 o;
  o.x = (v.x - mu) * r * gv.x + bv.x;
  o.y = (v.y - mu) * r * gv.y + bv.y;
  o.z = (v.z - mu) * r * gv.z + bv.z;
  o.w = (v.w - mu) * r * gv.w + bv.w;
  ((float4*)(out + off))[threadIdx.x] = o;
}

// ---------------------------------------------------------------------------
extern "C" void kernel_launch(void* const* d_in, const int* in_sizes, int n_in,
                              void* d_out, int out_size, void* d_ws, size_t ws_size,
                              hipStream_t stream)
{
  const float* x       = (const float*)d_in[0];
  const float* in_proj = (const float*)d_in[1];
  const float* conv_w  = (const float*)d_in[2];
  const float* conv_b  = (const float*)d_in[3];
  const float* x_proj  = (const float*)d_in[4];
  const float* dt_w    = (const float*)d_in[5];
  const float* dt_b    = (const float*)d_in[6];
  const float* A_log   = (const float*)d_in[7];
  const float* Dv      = (const float*)d_in[8];
  const float* out_w   = (const float*)d_in[9];
  const float* ln_g    = (const float*)d_in[10];
  const float* ln_bias = (const float*)d_in[11];
  float* out = (float*)d_out;

  char* w8 = (char*)d_ws;
  unsigned short* xz_bf = (unsigned short*)(w8 + 0);           // 33.55 MB
  unsigned short* xc_bf = (unsigned short*)(w8 + 33554432);    // 16.78 MB
  float*          xdbl  = (float*)(w8 + 50331648);             //  1.57 MB
  unsigned short* dty   = (unsigned short*)(w8 + 51904512);    // 16.78 MB (bf16 dt)
  unsigned short* y_bf  = (unsigned short*)(w8 + 68681728);    // 16.78 MB
  unsigned short* x_bf  = (unsigned short*)(w8 + 85458944);    //  8.39 MB (also dtr later)
  unsigned short* w_in  = (unsigned short*)(w8 + 93847552);    //  8.39 MB
  unsigned short* w_x   = (unsigned short*)(w8 + 102236160);   //  0.38 MB
  unsigned short* w_dt  = (unsigned short*)(w8 + 102629376);   //  0.26 MB
  unsigned short* w_out = (unsigned short*)(w8 + 102891520);   //  4.19 MB
  unsigned short* pbufx = (unsigned short*)(w8 + 107085824);   //  6.29 MB (bf16 x8)
  float*          PH    = (float*)(w8 + 113377280);            // 33.55 MB
  unsigned short* pbufo = xz_bf;                               // alias: 2x8.39 MB bf16

  dim3 blk(256);
  // 0) all fp32->bf16 casts in one dispatch
  cast5_k<<<dim3((N_ALL / 4 + 255) / 256), blk, 0, stream>>>(
      x, x_bf, in_proj, w_in, x_proj, w_x, dt_w, w_dt, out_w, w_out);
  // 1) in_proj MFMA -> xz_bf (bf16 out)
  mgemm<3><<<dim3(32, 32, 1), blk, 0, stream>>>(x_bf, 1024, w_in, 1024,
                                                xz_bf, 4096, 4096, 1024, nullptr, 0);
  // 2) conv + silu -> xc_bf
  conv_silu_k<<<dim3((NTOK * D_INNER / 4) / 256), blk, 0, stream>>>(
      xz_bf, conv_w, conv_b, xc_bf);
  // 3) x_proj MFMA, split-K=8 -> bf16 partials; fused reduce + dt_r cast -> x_bf
  mgemm<4><<<dim3(1, 32, 8), blk, 0, stream>>>(xc_bf, 2048, w_x, 2048,
                                               pbufx, 96, 96, 256, nullptr,
                                               (size_t)4096 * 96);
  redcast_k<<<dim3(4096 * 96 / 1024), blk, 0, stream>>>(pbufx, xdbl, x_bf /*dtr*/);
  // 4) dt_proj + softplus via MFMA (K=64) -> bf16 dt
  mgemm<1><<<dim3(16, 32, 1), blk, 0, stream>>>(x_bf /*dtr*/, 64, w_dt, 64,
                                                dty, 2048, 2048, 64, dt_b, 0);
  // 5) chunked selective scan -> y_bf
  scan_p1 <<<dim3(BSZ * NCHK * 2048 / 256), blk, 0, stream>>>(A_log, xdbl, xc_bf, dty, PH);
  scan_fix<<<dim3(BSZ * 2048 * 16 / 256), blk, 0, stream>>>(PH);
  scan_p2 <<<dim3(BSZ * NCHK * 2048 / 256), blk, 0, stream>>>(A_log, Dv, xdbl, xc_bf,
                                                              xz_bf, PH, dty, y_bf);
  // 6) out_proj MFMA, split-K=2 -> bf16 partials in pbufo (xz_bf dead after scan_p2)
  mgemm<4><<<dim3(8, 32, 2), blk, 0, stream>>>(y_bf, 2048, w_out, 2048,
                                               pbufo, 1024, 1024, 1024, nullptr,
                                               (size_t)4096 * 1024);
  // 7) fused reduce + residual + layernorm -> out
  ln2_k<<<dim3(NTOK), blk, 0, stream>>>(pbufo, pbufo + (size_t)4096 * 1024,
                                        x, ln_g, ln_bias, out);
}